// Round 1
// baseline (2825.257 us; speedup 1.0000x reference)
//
#include <hip/hip_runtime.h>
#include <cstdint>
#include <cstddef>

#define BS   8
#define C    256
#define C2   128
#define NPIX 4096

typedef unsigned short u16;
typedef unsigned int   u32;

__device__ __forceinline__ float bf2f(u16 u) {
    union { u32 i; float f; } x; x.i = ((u32)u) << 16; return x.f;
}
__device__ __forceinline__ u16 f2bf(float f) {
    union { float ff; u32 i; } x; x.ff = f;
    u32 r = x.i + 0x7fffu + ((x.i >> 16) & 1u);  // RNE
    return (u16)(r >> 16);
}

// out[b][o][n] = bias[o] + sum_c W[o][c] * x[b][c][n]   (fp32 in, bf16 out)
// grid: (N/64, O/64, BS), block 256. 64x64 tile, TK=16, 4x4 micro-tile.
template <int O, int CIN>
__global__ __launch_bounds__(256)
void proj_kernel(const float* __restrict__ W, const float* __restrict__ bias,
                 const float* __restrict__ x, u16* __restrict__ out) {
    __shared__ float Ws[16][65];   // [kk][o'], +1 pad to break write conflicts
    __shared__ float Xs[16][64];   // [kk][n']
    const int t  = threadIdx.x;
    const int tx = t & 15, ty = t >> 4;
    const int n0 = blockIdx.x * 64;
    const int o0 = blockIdx.y * 64;
    const int b  = blockIdx.z;
    float acc[4][4] = {{0.f, 0.f, 0.f, 0.f}};
    for (int kc = 0; kc < CIN; kc += 16) {
        #pragma unroll
        for (int idx0 = 0; idx0 < 1024; idx0 += 256) {
            const int idx = idx0 + t;
            const int oo = idx >> 4, kk = idx & 15;
            Ws[kk][oo] = W[(size_t)(o0 + oo) * CIN + (kc + kk)];
        }
        #pragma unroll
        for (int idx0 = 0; idx0 < 1024; idx0 += 256) {
            const int idx = idx0 + t;
            const int kk = idx >> 6, nn = idx & 63;
            Xs[kk][nn] = x[((size_t)b * CIN + (kc + kk)) * NPIX + (n0 + nn)];
        }
        __syncthreads();
        #pragma unroll
        for (int kk = 0; kk < 16; ++kk) {
            const float a0 = Ws[kk][ty * 4 + 0];
            const float a1 = Ws[kk][ty * 4 + 1];
            const float a2 = Ws[kk][ty * 4 + 2];
            const float a3 = Ws[kk][ty * 4 + 3];
            const float4 bv = *(const float4*)&Xs[kk][tx * 4];
            acc[0][0] = fmaf(a0, bv.x, acc[0][0]);
            acc[0][1] = fmaf(a0, bv.y, acc[0][1]);
            acc[0][2] = fmaf(a0, bv.z, acc[0][2]);
            acc[0][3] = fmaf(a0, bv.w, acc[0][3]);
            acc[1][0] = fmaf(a1, bv.x, acc[1][0]);
            acc[1][1] = fmaf(a1, bv.y, acc[1][1]);
            acc[1][2] = fmaf(a1, bv.z, acc[1][2]);
            acc[1][3] = fmaf(a1, bv.w, acc[1][3]);
            acc[2][0] = fmaf(a2, bv.x, acc[2][0]);
            acc[2][1] = fmaf(a2, bv.y, acc[2][1]);
            acc[2][2] = fmaf(a2, bv.z, acc[2][2]);
            acc[2][3] = fmaf(a2, bv.w, acc[2][3]);
            acc[3][0] = fmaf(a3, bv.x, acc[3][0]);
            acc[3][1] = fmaf(a3, bv.y, acc[3][1]);
            acc[3][2] = fmaf(a3, bv.z, acc[3][2]);
            acc[3][3] = fmaf(a3, bv.w, acc[3][3]);
        }
        __syncthreads();
    }
    #pragma unroll
    for (int ii = 0; ii < 4; ++ii) {
        const float bb = bias[o0 + ty * 4 + ii];
        const size_t base = ((size_t)b * O + (o0 + ty * 4 + ii)) * NPIX + n0 + tx * 4;
        #pragma unroll
        for (int jj = 0; jj < 4; ++jj)
            out[base + jj] = f2bf(acc[ii][jj] + bb);
    }
}

// One block per (b, 4 query rows). Energy row lives in registers (16 j-tiles
// of 256, j = tile*256 + tid). Exact softmax, then PV with thread-per-channel.
__global__ __launch_bounds__(256)
void attn_kernel(const u16* __restrict__ qw, const u16* __restrict__ kw,
                 const u16* __restrict__ vw, const float* __restrict__ motion,
                 float* __restrict__ fuse_out, float* __restrict__ outp) {
    __shared__ float qs[4][C2];
    __shared__ float pt[4][256];
    __shared__ float redmax[4][4];
    __shared__ float redsum[4][4];

    const int t  = threadIdx.x;
    const int b  = blockIdx.x & 7;          // batch<->XCD round-robin locality
    const int i0 = (blockIdx.x >> 3) << 2;  // query tile base

    #pragma unroll
    for (int idx0 = 0; idx0 < 512; idx0 += 256) {
        const int idx = idx0 + t;
        const int c = idx & (C2 - 1), r = idx >> 7;
        qs[r][c] = bf2f(qw[((size_t)b * C2 + c) * NPIX + (i0 + r)]);
    }
    __syncthreads();

    const u16* kb = kw + (size_t)b * C2 * NPIX;
    float e0[16], e1[16], e2[16], e3[16];
    #pragma unroll
    for (int xx = 0; xx < 16; ++xx) { e0[xx] = 0.f; e1[xx] = 0.f; e2[xx] = 0.f; e3[xx] = 0.f; }

    // QK^T: c-outer (hoists q LDS reads), 4 tile-chunks to bound live loads
    #pragma unroll
    for (int ch = 0; ch < 4; ++ch) {
        for (int c = 0; c < C2; c += 4) {
            const float4 qa = *(const float4*)&qs[0][c];
            const float4 qb = *(const float4*)&qs[1][c];
            const float4 qc = *(const float4*)&qs[2][c];
            const float4 qd = *(const float4*)&qs[3][c];
            const u16* kp = kb + (size_t)c * NPIX + (ch * 1024 + t);
            #pragma unroll
            for (int u = 0; u < 4; ++u) {
                const int tile = ch * 4 + u;
                const int off = u * 256;
                const float k0 = bf2f(kp[off]);
                const float k1 = bf2f(kp[NPIX + off]);
                const float k2 = bf2f(kp[2 * NPIX + off]);
                const float k3 = bf2f(kp[3 * NPIX + off]);
                e0[tile] = fmaf(qa.w, k3, fmaf(qa.z, k2, fmaf(qa.y, k1, fmaf(qa.x, k0, e0[tile]))));
                e1[tile] = fmaf(qb.w, k3, fmaf(qb.z, k2, fmaf(qb.y, k1, fmaf(qb.x, k0, e1[tile]))));
                e2[tile] = fmaf(qc.w, k3, fmaf(qc.z, k2, fmaf(qc.y, k1, fmaf(qc.x, k0, e2[tile]))));
                e3[tile] = fmaf(qd.w, k3, fmaf(qd.z, k2, fmaf(qd.y, k1, fmaf(qd.x, k0, e3[tile]))));
            }
        }
    }

    // softmax: block max
    float m0 = -1e30f, m1 = -1e30f, m2 = -1e30f, m3 = -1e30f;
    #pragma unroll
    for (int xx = 0; xx < 16; ++xx) {
        m0 = fmaxf(m0, e0[xx]); m1 = fmaxf(m1, e1[xx]);
        m2 = fmaxf(m2, e2[xx]); m3 = fmaxf(m3, e3[xx]);
    }
    #pragma unroll
    for (int o = 32; o > 0; o >>= 1) {
        m0 = fmaxf(m0, __shfl_down(m0, o, 64));
        m1 = fmaxf(m1, __shfl_down(m1, o, 64));
        m2 = fmaxf(m2, __shfl_down(m2, o, 64));
        m3 = fmaxf(m3, __shfl_down(m3, o, 64));
    }
    if ((t & 63) == 0) {
        const int w = t >> 6;
        redmax[0][w] = m0; redmax[1][w] = m1; redmax[2][w] = m2; redmax[3][w] = m3;
    }
    __syncthreads();
    m0 = fmaxf(fmaxf(redmax[0][0], redmax[0][1]), fmaxf(redmax[0][2], redmax[0][3]));
    m1 = fmaxf(fmaxf(redmax[1][0], redmax[1][1]), fmaxf(redmax[1][2], redmax[1][3]));
    m2 = fmaxf(fmaxf(redmax[2][0], redmax[2][1]), fmaxf(redmax[2][2], redmax[2][3]));
    m3 = fmaxf(fmaxf(redmax[3][0], redmax[3][1]), fmaxf(redmax[3][2], redmax[3][3]));

    // exp + block sum (p kept unnormalized; divide folded into epilogue)
    float s0 = 0.f, s1 = 0.f, s2 = 0.f, s3 = 0.f;
    #pragma unroll
    for (int xx = 0; xx < 16; ++xx) {
        e0[xx] = __expf(e0[xx] - m0); s0 += e0[xx];
        e1[xx] = __expf(e1[xx] - m1); s1 += e1[xx];
        e2[xx] = __expf(e2[xx] - m2); s2 += e2[xx];
        e3[xx] = __expf(e3[xx] - m3); s3 += e3[xx];
    }
    #pragma unroll
    for (int o = 32; o > 0; o >>= 1) {
        s0 += __shfl_down(s0, o, 64);
        s1 += __shfl_down(s1, o, 64);
        s2 += __shfl_down(s2, o, 64);
        s3 += __shfl_down(s3, o, 64);
    }
    if ((t & 63) == 0) {
        const int w = t >> 6;
        redsum[0][w] = s0; redsum[1][w] = s1; redsum[2][w] = s2; redsum[3][w] = s3;
    }
    __syncthreads();
    s0 = redsum[0][0] + redsum[0][1] + redsum[0][2] + redsum[0][3];
    s1 = redsum[1][0] + redsum[1][1] + redsum[1][2] + redsum[1][3];
    s2 = redsum[2][0] + redsum[2][1] + redsum[2][2] + redsum[2][3];
    s3 = redsum[3][0] + redsum[3][1] + redsum[3][2] + redsum[3][3];
    const float il0 = 1.f / s0, il1 = 1.f / s1, il2 = 1.f / s2, il3 = 1.f / s3;

    // PV: thread t owns channel c=t; P broadcast via LDS tile
    const u16* vrow = vw + ((size_t)b * C + t) * NPIX;
    float a0 = 0.f, a1 = 0.f, a2 = 0.f, a3 = 0.f;
    #pragma unroll
    for (int tile = 0; tile < 16; ++tile) {
        __syncthreads();  // protect pt from previous iteration's readers
        pt[0][t] = e0[tile]; pt[1][t] = e1[tile]; pt[2][t] = e2[tile]; pt[3][t] = e3[tile];
        __syncthreads();
        const u16* vp = vrow + tile * 256;
        for (int jj = 0; jj < 256; jj += 4) {
            const uint2 vv = *(const uint2*)&vp[jj];
            union { u32 i; float f; } cv;
            float v0, v1, v2, v3;
            cv.i = vv.x << 16;          v0 = cv.f;
            cv.i = vv.x & 0xffff0000u;  v1 = cv.f;
            cv.i = vv.y << 16;          v2 = cv.f;
            cv.i = vv.y & 0xffff0000u;  v3 = cv.f;
            const float4 p0 = *(const float4*)&pt[0][jj];
            const float4 p1 = *(const float4*)&pt[1][jj];
            const float4 p2 = *(const float4*)&pt[2][jj];
            const float4 p3 = *(const float4*)&pt[3][jj];
            a0 = fmaf(v3, p0.w, fmaf(v2, p0.z, fmaf(v1, p0.y, fmaf(v0, p0.x, a0))));
            a1 = fmaf(v3, p1.w, fmaf(v2, p1.z, fmaf(v1, p1.y, fmaf(v0, p1.x, a1))));
            a2 = fmaf(v3, p2.w, fmaf(v2, p2.z, fmaf(v1, p2.y, fmaf(v0, p2.x, a2))));
            a3 = fmaf(v3, p3.w, fmaf(v2, p3.z, fmaf(v1, p3.y, fmaf(v0, p3.x, a3))));
        }
    }

    const size_t base = ((size_t)b * C + t) * NPIX + i0;
    const float4 mv = *(const float4*)&motion[base];
    const float o0v = a0 * il0, o1v = a1 * il1, o2v = a2 * il2, o3v = a3 * il3;
    const float4 ov = make_float4(o0v, o1v, o2v, o3v);
    const float4 fv = make_float4(o0v * mv.x, o1v * mv.y, o2v * mv.z, o3v * mv.w);
    *(float4*)&outp[base]     = ov;
    *(float4*)&fuse_out[base] = fv;
}

extern "C" void kernel_launch(void* const* d_in, const int* in_sizes, int n_in,
                              void* d_out, int out_size, void* d_ws, size_t ws_size,
                              hipStream_t stream) {
    const float* a1     = (const float*)d_in[0];  // appearance_1 -> k
    const float* a2     = (const float*)d_in[1];  // appearance_2 -> q
    const float* motion = (const float*)d_in[2];  // -> v, and fuse multiplier
    const float* Wq = (const float*)d_in[3];
    const float* bq = (const float*)d_in[4];
    const float* Wk = (const float*)d_in[5];
    const float* bk = (const float*)d_in[6];
    const float* Wv = (const float*)d_in[7];
    const float* bv = (const float*)d_in[8];

    float* outp = (float*)d_out;  // [0, BS*C*NPIX) = fuse_out, then out

    // workspace: q (8MB) | k (8MB) | v (16MB), all bf16
    u16* qws = (u16*)d_ws;
    u16* kws = qws + (size_t)BS * C2 * NPIX;
    u16* vws = kws + (size_t)BS * C2 * NPIX;

    const dim3 blk(256);
    proj_kernel<C2, C2><<<dim3(NPIX / 64, C2 / 64, BS), blk, 0, stream>>>(Wq, bq, a2, qws);
    proj_kernel<C2, C2><<<dim3(NPIX / 64, C2 / 64, BS), blk, 0, stream>>>(Wk, bk, a1, kws);
    proj_kernel<C, C><<<dim3(NPIX / 64, C / 64, BS), blk, 0, stream>>>(Wv, bv, motion, vws);

    attn_kernel<<<dim3(BS * (NPIX / 4)), blk, 0, stream>>>(
        qws, kws, vws, motion, outp, outp + (size_t)BS * C * NPIX);
}

// Round 2
// 979.669 us; speedup vs baseline: 2.8839x; 2.8839x over previous
//
#include <hip/hip_runtime.h>
#include <cstdint>
#include <cstddef>

#define BS   8
#define C    256
#define C2   128
#define NPIX 4096

typedef unsigned short u16;
typedef unsigned int   u32;
typedef __bf16 bf16_t;
typedef bf16_t bf16x8 __attribute__((ext_vector_type(8)));
typedef float  f32x4  __attribute__((ext_vector_type(4)));

__device__ __forceinline__ u16 f2bf(float f) {
    union { float ff; u32 i; } x; x.ff = f;
    u32 r = x.i + 0x7fffu + ((x.i >> 16) & 1u);  // RNE
    return (u16)(r >> 16);
}

// ---------------- projection, natural output [b][o][n] (used for V) --------
template <int O, int CIN>
__global__ __launch_bounds__(256)
void proj_nat(const float* __restrict__ W, const float* __restrict__ bias,
              const float* __restrict__ x, u16* __restrict__ out) {
    __shared__ float Ws[16][65];
    __shared__ float Xs[16][64];
    const int t  = threadIdx.x;
    const int tx = t & 15, ty = t >> 4;
    const int n0 = blockIdx.x * 64;
    const int o0 = blockIdx.y * 64;
    const int b  = blockIdx.z;
    float acc[4][4] = {{0.f,0.f,0.f,0.f}};
    for (int kc = 0; kc < CIN; kc += 16) {
        #pragma unroll
        for (int idx0 = 0; idx0 < 1024; idx0 += 256) {
            const int idx = idx0 + t;
            const int oo = idx >> 4, kk = idx & 15;
            Ws[kk][oo] = W[(size_t)(o0 + oo) * CIN + (kc + kk)];
        }
        #pragma unroll
        for (int idx0 = 0; idx0 < 1024; idx0 += 256) {
            const int idx = idx0 + t;
            const int kk = idx >> 6, nn = idx & 63;
            Xs[kk][nn] = x[((size_t)b * CIN + (kc + kk)) * NPIX + (n0 + nn)];
        }
        __syncthreads();
        #pragma unroll
        for (int kk = 0; kk < 16; ++kk) {
            const float a0 = Ws[kk][ty * 4 + 0];
            const float a1 = Ws[kk][ty * 4 + 1];
            const float a2 = Ws[kk][ty * 4 + 2];
            const float a3 = Ws[kk][ty * 4 + 3];
            const float4 bv = *(const float4*)&Xs[kk][tx * 4];
            acc[0][0] = fmaf(a0, bv.x, acc[0][0]); acc[0][1] = fmaf(a0, bv.y, acc[0][1]);
            acc[0][2] = fmaf(a0, bv.z, acc[0][2]); acc[0][3] = fmaf(a0, bv.w, acc[0][3]);
            acc[1][0] = fmaf(a1, bv.x, acc[1][0]); acc[1][1] = fmaf(a1, bv.y, acc[1][1]);
            acc[1][2] = fmaf(a1, bv.z, acc[1][2]); acc[1][3] = fmaf(a1, bv.w, acc[1][3]);
            acc[2][0] = fmaf(a2, bv.x, acc[2][0]); acc[2][1] = fmaf(a2, bv.y, acc[2][1]);
            acc[2][2] = fmaf(a2, bv.z, acc[2][2]); acc[2][3] = fmaf(a2, bv.w, acc[2][3]);
            acc[3][0] = fmaf(a3, bv.x, acc[3][0]); acc[3][1] = fmaf(a3, bv.y, acc[3][1]);
            acc[3][2] = fmaf(a3, bv.z, acc[3][2]); acc[3][3] = fmaf(a3, bv.w, acc[3][3]);
        }
        __syncthreads();
    }
    #pragma unroll
    for (int ii = 0; ii < 4; ++ii) {
        const float bb = bias[o0 + ty * 4 + ii];
        const size_t base = ((size_t)b * O + (o0 + ty * 4 + ii)) * NPIX + n0 + tx * 4;
        u16 tmp[4];
        #pragma unroll
        for (int jj = 0; jj < 4; ++jj) tmp[jj] = f2bf(acc[ii][jj] + bb);
        *(uint2*)&out[base] = make_uint2((u32)tmp[0] | ((u32)tmp[1] << 16),
                                         (u32)tmp[2] | ((u32)tmp[3] << 16));
    }
}

// ------------- projection, transposed output [b][n][o]  (used for Q, K) ----
// O == CIN == 128. Same GEMM core; epilogue transposes through LDS so the
// global stores are contiguous 16B chunks along o.
__global__ __launch_bounds__(256)
void proj_t(const float* __restrict__ W, const float* __restrict__ bias,
            const float* __restrict__ x, u16* __restrict__ out) {
    __shared__ float Ws[16][65];
    __shared__ float Xs[16][64];
    __shared__ float T[64][66];
    const int t  = threadIdx.x;
    const int tx = t & 15, ty = t >> 4;
    const int n0 = blockIdx.x * 64;
    const int o0 = blockIdx.y * 64;
    const int b  = blockIdx.z;
    float acc[4][4] = {{0.f,0.f,0.f,0.f}};
    for (int kc = 0; kc < 128; kc += 16) {
        #pragma unroll
        for (int idx0 = 0; idx0 < 1024; idx0 += 256) {
            const int idx = idx0 + t;
            const int oo = idx >> 4, kk = idx & 15;
            Ws[kk][oo] = W[(size_t)(o0 + oo) * 128 + (kc + kk)];
        }
        #pragma unroll
        for (int idx0 = 0; idx0 < 1024; idx0 += 256) {
            const int idx = idx0 + t;
            const int kk = idx >> 6, nn = idx & 63;
            Xs[kk][nn] = x[((size_t)b * 128 + (kc + kk)) * NPIX + (n0 + nn)];
        }
        __syncthreads();
        #pragma unroll
        for (int kk = 0; kk < 16; ++kk) {
            const float a0 = Ws[kk][ty * 4 + 0];
            const float a1 = Ws[kk][ty * 4 + 1];
            const float a2 = Ws[kk][ty * 4 + 2];
            const float a3 = Ws[kk][ty * 4 + 3];
            const float4 bv = *(const float4*)&Xs[kk][tx * 4];
            acc[0][0] = fmaf(a0, bv.x, acc[0][0]); acc[0][1] = fmaf(a0, bv.y, acc[0][1]);
            acc[0][2] = fmaf(a0, bv.z, acc[0][2]); acc[0][3] = fmaf(a0, bv.w, acc[0][3]);
            acc[1][0] = fmaf(a1, bv.x, acc[1][0]); acc[1][1] = fmaf(a1, bv.y, acc[1][1]);
            acc[1][2] = fmaf(a1, bv.z, acc[1][2]); acc[1][3] = fmaf(a1, bv.w, acc[1][3]);
            acc[2][0] = fmaf(a2, bv.x, acc[2][0]); acc[2][1] = fmaf(a2, bv.y, acc[2][1]);
            acc[2][2] = fmaf(a2, bv.z, acc[2][2]); acc[2][3] = fmaf(a2, bv.w, acc[2][3]);
            acc[3][0] = fmaf(a3, bv.x, acc[3][0]); acc[3][1] = fmaf(a3, bv.y, acc[3][1]);
            acc[3][2] = fmaf(a3, bv.z, acc[3][2]); acc[3][3] = fmaf(a3, bv.w, acc[3][3]);
        }
        __syncthreads();
    }
    #pragma unroll
    for (int ii = 0; ii < 4; ++ii) {
        const float bb = bias[o0 + ty * 4 + ii];
        #pragma unroll
        for (int jj = 0; jj < 4; ++jj)
            T[tx * 4 + jj][ty * 4 + ii] = acc[ii][jj] + bb;
    }
    __syncthreads();
    const int n = t >> 2, oq = t & 3;
    u16 tmp[16];
    #pragma unroll
    for (int e = 0; e < 16; ++e) tmp[e] = f2bf(T[n][oq * 16 + e]);
    u16* op = out + ((size_t)b * NPIX + n0 + n) * 128 + o0 + oq * 16;
    uint4 w0, w1;
    w0.x = (u32)tmp[0]  | ((u32)tmp[1]  << 16); w0.y = (u32)tmp[2]  | ((u32)tmp[3]  << 16);
    w0.z = (u32)tmp[4]  | ((u32)tmp[5]  << 16); w0.w = (u32)tmp[6]  | ((u32)tmp[7]  << 16);
    w1.x = (u32)tmp[8]  | ((u32)tmp[9]  << 16); w1.y = (u32)tmp[10] | ((u32)tmp[11] << 16);
    w1.z = (u32)tmp[12] | ((u32)tmp[13] << 16); w1.w = (u32)tmp[14] | ((u32)tmp[15] << 16);
    *(uint4*)op = w0;
    *(uint4*)(op + 8) = w1;
}

// ----------------------------- MFMA attention ------------------------------
// Block = 64 queries (4 waves x 16 rows). Single-pass softmax (no max-sub:
// |energy| <~ 30 so exp/sums stay in fp32 range). Per j-tile (64 keys):
//   S = Q^T K via mfma 16x16x32 (A from QT[n][c], B from KT[n][c]),
//   P = exp(S) -> LDS (C-layout -> A-layout round trip),
//   O += P V via mfma (B from natural V[c][n]).
__global__ __launch_bounds__(256, 2)
void attn_mfma(const u16* __restrict__ qt,   // [BS][NPIX][C2]
               const u16* __restrict__ kt,   // [BS][NPIX][C2]
               const u16* __restrict__ vn,   // [BS][C][NPIX]
               const float* __restrict__ motion,
               float* __restrict__ fuse_out, float* __restrict__ outp) {
    __shared__ u16  pbuf[4][16 * 72];  // per-wave P tile, stride 72 keeps b128 reads 16B-aligned
    __shared__ float ot[64][129];      // epilogue transpose buffer (one c-half at a time)

    const int t    = threadIdx.x;
    const int w    = t >> 6;
    const int lane = t & 63;
    const int L    = lane & 15;
    const int quad = lane >> 4;

    const int b   = blockIdx.x & 7;        // batch <-> XCD affinity
    const int it  = blockIdx.x >> 3;
    const int i0  = it * 64;
    const int i0w = i0 + w * 16;

    // Q fragments: A[m=i=L][k=c=cc*32+quad*8+e], persistent in registers
    bf16x8 aq[4];
    {
        const u16* qp = qt + ((size_t)b * NPIX + i0w + L) * C2 + quad * 8;
        #pragma unroll
        for (int cc = 0; cc < 4; ++cc)
            aq[cc] = *(const bf16x8*)(qp + cc * 32);
    }

    f32x4 oacc[16];
    #pragma unroll
    for (int cc = 0; cc < 16; ++cc) oacc[cc] = (f32x4){0.f, 0.f, 0.f, 0.f};
    float ssum[4] = {0.f, 0.f, 0.f, 0.f};

    const u16* kbase = kt + (size_t)b * NPIX * C2;
    const u16* vbase = vn + (size_t)b * C * NPIX;
    u16* pw = &pbuf[w][0];

    for (int jt = 0; jt < NPIX; jt += 64) {
        // ---- S tile [16 i x 64 j]
        f32x4 s[4];
        #pragma unroll
        for (int jc = 0; jc < 4; ++jc) s[jc] = (f32x4){0.f, 0.f, 0.f, 0.f};
        #pragma unroll
        for (int cc = 0; cc < 4; ++cc) {
            #pragma unroll
            for (int jc = 0; jc < 4; ++jc) {
                const u16* kp = kbase + (size_t)(jt + jc * 16 + L) * C2 + cc * 32 + quad * 8;
                bf16x8 bk = *(const bf16x8*)kp;
                s[jc] = __builtin_amdgcn_mfma_f32_16x16x32_bf16(aq[cc], bk, s[jc], 0, 0, 0);
            }
        }
        // ---- P = exp(S), row-sum partials, store to per-wave LDS [i][j]
        #pragma unroll
        for (int jc = 0; jc < 4; ++jc) {
            #pragma unroll
            for (int r = 0; r < 4; ++r) {
                const float p = __expf(s[jc][r]);
                ssum[r] += p;
                pw[(quad * 4 + r) * 72 + jc * 16 + L] = f2bf(p);
            }
        }
        // ---- P as A-fragments (wave-private buffer; in-wave DS ordering)
        const bf16x8 ap0 = *(const bf16x8*)(pw + L * 72 + quad * 8);
        const bf16x8 ap1 = *(const bf16x8*)(pw + L * 72 + 32 + quad * 8);
        // ---- O += P * V
        #pragma unroll
        for (int cc = 0; cc < 16; ++cc) {
            const u16* vp = vbase + (size_t)(cc * 16 + L) * NPIX + jt + quad * 8;
            const bf16x8 bv0 = *(const bf16x8*)vp;
            const bf16x8 bv1 = *(const bf16x8*)(vp + 32);
            oacc[cc] = __builtin_amdgcn_mfma_f32_16x16x32_bf16(ap0, bv0, oacc[cc], 0, 0, 0);
            oacc[cc] = __builtin_amdgcn_mfma_f32_16x16x32_bf16(ap1, bv1, oacc[cc], 0, 0, 0);
        }
    }

    // ---- finalize row sums (reduce across the 16 lanes holding each row)
    #pragma unroll
    for (int r = 0; r < 4; ++r) {
        float s = ssum[r];
        s += __shfl_xor(s, 1);
        s += __shfl_xor(s, 2);
        s += __shfl_xor(s, 4);
        s += __shfl_xor(s, 8);
        ssum[r] = 1.0f / s;
    }

    // ---- epilogue: normalize, transpose 64x128 halves through LDS, store
    #pragma unroll
    for (int h = 0; h < 2; ++h) {
        __syncthreads();
        #pragma unroll
        for (int cc8 = 0; cc8 < 8; ++cc8) {
            const int cc = h * 8 + cc8;
            #pragma unroll
            for (int r = 0; r < 4; ++r)
                ot[w * 16 + quad * 4 + r][cc8 * 16 + L] = oacc[cc][r] * ssum[r];
        }
        __syncthreads();
        const int cl = t >> 1;
        const int ih = (t & 1) * 32;
        const int c  = h * 128 + cl;
        const size_t gbase = ((size_t)b * C + c) * NPIX + i0 + ih;
        #pragma unroll
        for (int k4 = 0; k4 < 8; ++k4) {
            float4 o4;
            o4.x = ot[ih + k4 * 4 + 0][cl];
            o4.y = ot[ih + k4 * 4 + 1][cl];
            o4.z = ot[ih + k4 * 4 + 2][cl];
            o4.w = ot[ih + k4 * 4 + 3][cl];
            const float4 mv = *(const float4*)&motion[gbase + k4 * 4];
            *(float4*)&outp[gbase + k4 * 4] = o4;
            const float4 f4 = make_float4(o4.x * mv.x, o4.y * mv.y, o4.z * mv.z, o4.w * mv.w);
            *(float4*)&fuse_out[gbase + k4 * 4] = f4;
        }
    }
}

extern "C" void kernel_launch(void* const* d_in, const int* in_sizes, int n_in,
                              void* d_out, int out_size, void* d_ws, size_t ws_size,
                              hipStream_t stream) {
    const float* a1     = (const float*)d_in[0];  // appearance_1 -> k
    const float* a2     = (const float*)d_in[1];  // appearance_2 -> q
    const float* motion = (const float*)d_in[2];  // -> v, and fuse multiplier
    const float* Wq = (const float*)d_in[3];
    const float* bq = (const float*)d_in[4];
    const float* Wk = (const float*)d_in[5];
    const float* bk = (const float*)d_in[6];
    const float* Wv = (const float*)d_in[7];
    const float* bv = (const float*)d_in[8];

    float* outp = (float*)d_out;  // [fuse_out | out]

    // workspace: QT (8MB, [b][n][c]) | KT (8MB, [b][n][c]) | V (16MB, [b][c][n])
    u16* qws = (u16*)d_ws;
    u16* kws = qws + (size_t)BS * C2 * NPIX;
    u16* vws = kws + (size_t)BS * C2 * NPIX;

    const dim3 blk(256);
    proj_t<<<dim3(NPIX / 64, 2, BS), blk, 0, stream>>>(Wq, bq, a2, qws);
    proj_t<<<dim3(NPIX / 64, 2, BS), blk, 0, stream>>>(Wk, bk, a1, kws);
    proj_nat<C, C><<<dim3(NPIX / 64, C / 64, BS), blk, 0, stream>>>(Wv, bv, motion, vws);

    attn_mfma<<<dim3(BS * (NPIX / 64)), blk, 0, stream>>>(
        qws, kws, vws, motion, outp, outp + (size_t)BS * C * NPIX);
}

// Round 3
// 603.103 us; speedup vs baseline: 4.6845x; 1.6244x over previous
//
#include <hip/hip_runtime.h>
#include <cstdint>
#include <cstddef>

#define BS   8
#define C    256
#define C2   128
#define NPIX 4096

typedef unsigned short u16;
typedef unsigned int   u32;
typedef __bf16 bf16_t;
typedef bf16_t bf16x8 __attribute__((ext_vector_type(8)));
typedef float  f32x4  __attribute__((ext_vector_type(4)));
typedef float  f32x16 __attribute__((ext_vector_type(16)));

__device__ __forceinline__ u16 f2bf(float f) {
    union { float ff; u32 i; } x; x.ff = f;
    u32 r = x.i + 0x7fffu + ((x.i >> 16) & 1u);  // RNE
    return (u16)(r >> 16);
}

// ---------------- projection, natural output [b][o][n] (used for V) --------
template <int O, int CIN>
__global__ __launch_bounds__(256)
void proj_nat(const float* __restrict__ W, const float* __restrict__ bias,
              const float* __restrict__ x, u16* __restrict__ out) {
    __shared__ float Ws[16][65];
    __shared__ float Xs[16][64];
    const int t  = threadIdx.x;
    const int tx = t & 15, ty = t >> 4;
    const int n0 = blockIdx.x * 64;
    const int o0 = blockIdx.y * 64;
    const int b  = blockIdx.z;
    float acc[4][4] = {{0.f,0.f,0.f,0.f}};
    for (int kc = 0; kc < CIN; kc += 16) {
        #pragma unroll
        for (int idx0 = 0; idx0 < 1024; idx0 += 256) {
            const int idx = idx0 + t;
            const int oo = idx >> 4, kk = idx & 15;
            Ws[kk][oo] = W[(size_t)(o0 + oo) * CIN + (kc + kk)];
        }
        #pragma unroll
        for (int idx0 = 0; idx0 < 1024; idx0 += 256) {
            const int idx = idx0 + t;
            const int kk = idx >> 6, nn = idx & 63;
            Xs[kk][nn] = x[((size_t)b * CIN + (kc + kk)) * NPIX + (n0 + nn)];
        }
        __syncthreads();
        #pragma unroll
        for (int kk = 0; kk < 16; ++kk) {
            const float a0 = Ws[kk][ty * 4 + 0];
            const float a1 = Ws[kk][ty * 4 + 1];
            const float a2 = Ws[kk][ty * 4 + 2];
            const float a3 = Ws[kk][ty * 4 + 3];
            const float4 bv = *(const float4*)&Xs[kk][tx * 4];
            acc[0][0] = fmaf(a0, bv.x, acc[0][0]); acc[0][1] = fmaf(a0, bv.y, acc[0][1]);
            acc[0][2] = fmaf(a0, bv.z, acc[0][2]); acc[0][3] = fmaf(a0, bv.w, acc[0][3]);
            acc[1][0] = fmaf(a1, bv.x, acc[1][0]); acc[1][1] = fmaf(a1, bv.y, acc[1][1]);
            acc[1][2] = fmaf(a1, bv.z, acc[1][2]); acc[1][3] = fmaf(a1, bv.w, acc[1][3]);
            acc[2][0] = fmaf(a2, bv.x, acc[2][0]); acc[2][1] = fmaf(a2, bv.y, acc[2][1]);
            acc[2][2] = fmaf(a2, bv.z, acc[2][2]); acc[2][3] = fmaf(a2, bv.w, acc[2][3]);
            acc[3][0] = fmaf(a3, bv.x, acc[3][0]); acc[3][1] = fmaf(a3, bv.y, acc[3][1]);
            acc[3][2] = fmaf(a3, bv.z, acc[3][2]); acc[3][3] = fmaf(a3, bv.w, acc[3][3]);
        }
        __syncthreads();
    }
    #pragma unroll
    for (int ii = 0; ii < 4; ++ii) {
        const float bb = bias[o0 + ty * 4 + ii];
        const size_t base = ((size_t)b * O + (o0 + ty * 4 + ii)) * NPIX + n0 + tx * 4;
        u16 tmp[4];
        #pragma unroll
        for (int jj = 0; jj < 4; ++jj) tmp[jj] = f2bf(acc[ii][jj] + bb);
        *(uint2*)&out[base] = make_uint2((u32)tmp[0] | ((u32)tmp[1] << 16),
                                         (u32)tmp[2] | ((u32)tmp[3] << 16));
    }
}

// ------------- projection, transposed output [b][n][o]  (used for Q, K) ----
__global__ __launch_bounds__(256)
void proj_t(const float* __restrict__ W, const float* __restrict__ bias,
            const float* __restrict__ x, u16* __restrict__ out) {
    __shared__ float Ws[16][65];
    __shared__ float Xs[16][64];
    __shared__ float T[64][66];
    const int t  = threadIdx.x;
    const int tx = t & 15, ty = t >> 4;
    const int n0 = blockIdx.x * 64;
    const int o0 = blockIdx.y * 64;
    const int b  = blockIdx.z;
    float acc[4][4] = {{0.f,0.f,0.f,0.f}};
    for (int kc = 0; kc < 128; kc += 16) {
        #pragma unroll
        for (int idx0 = 0; idx0 < 1024; idx0 += 256) {
            const int idx = idx0 + t;
            const int oo = idx >> 4, kk = idx & 15;
            Ws[kk][oo] = W[(size_t)(o0 + oo) * 128 + (kc + kk)];
        }
        #pragma unroll
        for (int idx0 = 0; idx0 < 1024; idx0 += 256) {
            const int idx = idx0 + t;
            const int kk = idx >> 6, nn = idx & 63;
            Xs[kk][nn] = x[((size_t)b * 128 + (kc + kk)) * NPIX + (n0 + nn)];
        }
        __syncthreads();
        #pragma unroll
        for (int kk = 0; kk < 16; ++kk) {
            const float a0 = Ws[kk][ty * 4 + 0];
            const float a1 = Ws[kk][ty * 4 + 1];
            const float a2 = Ws[kk][ty * 4 + 2];
            const float a3 = Ws[kk][ty * 4 + 3];
            const float4 bv = *(const float4*)&Xs[kk][tx * 4];
            acc[0][0] = fmaf(a0, bv.x, acc[0][0]); acc[0][1] = fmaf(a0, bv.y, acc[0][1]);
            acc[0][2] = fmaf(a0, bv.z, acc[0][2]); acc[0][3] = fmaf(a0, bv.w, acc[0][3]);
            acc[1][0] = fmaf(a1, bv.x, acc[1][0]); acc[1][1] = fmaf(a1, bv.y, acc[1][1]);
            acc[1][2] = fmaf(a1, bv.z, acc[1][2]); acc[1][3] = fmaf(a1, bv.w, acc[1][3]);
            acc[2][0] = fmaf(a2, bv.x, acc[2][0]); acc[2][1] = fmaf(a2, bv.y, acc[2][1]);
            acc[2][2] = fmaf(a2, bv.z, acc[2][2]); acc[2][3] = fmaf(a2, bv.w, acc[2][3]);
            acc[3][0] = fmaf(a3, bv.x, acc[3][0]); acc[3][1] = fmaf(a3, bv.y, acc[3][1]);
            acc[3][2] = fmaf(a3, bv.z, acc[3][2]); acc[3][3] = fmaf(a3, bv.w, acc[3][3]);
        }
        __syncthreads();
    }
    #pragma unroll
    for (int ii = 0; ii < 4; ++ii) {
        const float bb = bias[o0 + ty * 4 + ii];
        #pragma unroll
        for (int jj = 0; jj < 4; ++jj)
            T[tx * 4 + jj][ty * 4 + ii] = acc[ii][jj] + bb;
    }
    __syncthreads();
    const int n = t >> 2, oq = t & 3;
    u16 tmp[16];
    #pragma unroll
    for (int e = 0; e < 16; ++e) tmp[e] = f2bf(T[n][oq * 16 + e]);
    u16* op = out + ((size_t)b * NPIX + n0 + n) * 128 + o0 + oq * 16;
    uint4 w0, w1;
    w0.x = (u32)tmp[0]  | ((u32)tmp[1]  << 16); w0.y = (u32)tmp[2]  | ((u32)tmp[3]  << 16);
    w0.z = (u32)tmp[4]  | ((u32)tmp[5]  << 16); w0.w = (u32)tmp[6]  | ((u32)tmp[7]  << 16);
    w1.x = (u32)tmp[8]  | ((u32)tmp[9]  << 16); w1.y = (u32)tmp[10] | ((u32)tmp[11] << 16);
    w1.z = (u32)tmp[12] | ((u32)tmp[13] << 16); w1.w = (u32)tmp[14] | ((u32)tmp[15] << 16);
    *(uint4*)op = w0;
    *(uint4*)(op + 8) = w1;
}

// ----------------------------- MFMA attention v2 ---------------------------
// Block = 4 waves; wave owns a 32x32 query tile (TI=128/block). TJ=64 keys
// per iteration, K-tile (16KB) + V-tile (32KB) double-buffered in LDS with
// XOR-swizzled 16B chunks (conflict-floor reads/writes). S' = K*Q^T so the
// C-layout column is the query index: row sums are in-lane, and P' reaches
// the PV B-operand via a single half-swap shuffle (no LDS round trip).
struct StageRegs { uint4 kr[4]; uint4 vr[8]; };

__device__ __forceinline__ void stage_load(const u16* __restrict__ kg,
                                           const u16* __restrict__ vg,
                                           int t, StageRegs& R) {
    #pragma unroll
    for (int kq = 0; kq < 4; ++kq)
        R.kr[kq] = *(const uint4*)(kg + (size_t)(t + 256 * kq) * 8);
    #pragma unroll
    for (int vq = 0; vq < 8; ++vq)
        R.vr[vq] = *(const uint4*)(vg + (size_t)((t >> 3) + 32 * vq) * NPIX + (t & 7) * 8);
}

__device__ __forceinline__ void stage_write(u16* __restrict__ kb, u16* __restrict__ vb,
                                            int t, const StageRegs& R) {
    #pragma unroll
    for (int kq = 0; kq < 4; ++kq) {
        const int q = t + 256 * kq;
        const int row = q >> 4;
        const int chs = (q & 15) ^ (row & 15);
        *(uint4*)(kb + row * 128 + chs * 8) = R.kr[kq];
    }
    #pragma unroll
    for (int vq = 0; vq < 8; ++vq) {
        const int c = (t >> 3) + 32 * vq;
        const int chs = (t & 7) ^ (c & 7);
        *(uint4*)(vb + c * 64 + chs * 8) = R.vr[vq];
    }
}

__global__ __launch_bounds__(256, 1)
void attn_mfma2(const u16* __restrict__ qt,   // [BS][NPIX][C2]
                const u16* __restrict__ kt,   // [BS][NPIX][C2]
                const u16* __restrict__ vn,   // [BS][C][NPIX]
                const float* __restrict__ motion,
                float* __restrict__ fuse_out, float* __restrict__ outp) {
    __shared__ u16 Kb[2][64 * 128];   // row j: 256B, chunk16' = chunk16 ^ (j&15)
    __shared__ u16 Vb[2][256 * 64];   // row c: 128B, chunk16' = chunk16 ^ (c&7)

    const int t  = threadIdx.x;
    const int w  = t >> 6;
    const int li = t & 31;
    const int hs = (t >> 5) & 1;

    const int b  = blockIdx.x & 7;          // batch <-> XCD affinity
    const int i0 = (blockIdx.x >> 3) * 128;
    const int iw = i0 + w * 32 + li;        // this lane's query column

    // Q fragments (persistent): B[k=c][n=i], slot (hs,e) -> c = ct*16 + hs*8 + e
    bf16x8 qf[8];
    {
        const u16* qp = qt + ((size_t)b * NPIX + iw) * C2 + hs * 8;
        #pragma unroll
        for (int ct = 0; ct < 8; ++ct) qf[ct] = *(const bf16x8*)(qp + ct * 16);
    }

    f32x16 oacc[8];
    #pragma unroll
    for (int ct = 0; ct < 8; ++ct)
        #pragma unroll
        for (int e = 0; e < 16; ++e) oacc[ct][e] = 0.f;

    const u16* ktb = kt + (size_t)b * NPIX * C2;
    const u16* vnb = vn + (size_t)b * C * NPIX;

    StageRegs R;
    stage_load(ktb, vnb, t, R);                       // tile 0
    stage_write(&Kb[0][0], &Vb[0][0], t, R);
    stage_load(ktb + 64 * 128, vnb + 64, t, R);       // tile 1 (in flight)
    __syncthreads();

    float ssl = 0.f;
    for (int it = 0; it < 64; ++it) {
        const int cur = it & 1;
        if (it < 63) {
            stage_write(&Kb[cur ^ 1][0], &Vb[cur ^ 1][0], t, R);   // tile it+1
            if (it < 62)
                stage_load(ktb + (size_t)(it + 2) * 64 * 128, vnb + (it + 2) * 64, t, R);
        }
        const u16* kb = &Kb[cur][0];
        const u16* vb = &Vb[cur][0];

        // ---- S' = K Q^T  [64j x 32i], two 32x32 tiles, k = c (8 chunks)
        f32x16 s[2];
        #pragma unroll
        for (int jc = 0; jc < 2; ++jc) {
            #pragma unroll
            for (int e = 0; e < 16; ++e) s[jc][e] = 0.f;
            const int jj = jc * 32 + li;
            const int xr = jj & 15;
            #pragma unroll
            for (int ct = 0; ct < 8; ++ct) {
                const int chs = (ct * 2 + hs) ^ xr;
                const bf16x8 kf = *(const bf16x8*)(kb + jj * 128 + chs * 8);
                s[jc] = __builtin_amdgcn_mfma_f32_32x32x16_bf16(kf, qf[ct], s[jc], 0, 0, 0);
            }
        }

        // ---- P = exp(S'), in-lane row-sum partials, pack to bf16 pairs
        u32 pk[2][8];
        #pragma unroll
        for (int jc = 0; jc < 2; ++jc)
            #pragma unroll
            for (int n = 0; n < 8; ++n) {
                const float p0 = __expf(s[jc][2 * n]);
                const float p1 = __expf(s[jc][2 * n + 1]);
                ssl += p0 + p1;
                pk[jc][n] = (u32)f2bf(p0) | ((u32)f2bf(p1) << 16);
            }

        // ---- P' -> PV B-fragments via half-swap shuffle
        bf16x8 pf[4];
        #pragma unroll
        for (int seg = 0; seg < 4; ++seg) {
            const int jc = seg >> 1, s2 = seg & 1;
            const u32 A0 = pk[jc][4 * s2 + 0], A1 = pk[jc][4 * s2 + 1];
            const u32 A2 = pk[jc][4 * s2 + 2], A3 = pk[jc][4 * s2 + 3];
            const u32 own0 = hs ? A2 : A0, own1 = hs ? A3 : A1;
            const u32 snd0 = hs ? A0 : A2, snd1 = hs ? A1 : A3;
            const u32 rcv0 = (u32)__shfl_xor((int)snd0, 32, 64);
            const u32 rcv1 = (u32)__shfl_xor((int)snd1, 32, 64);
            union { u32 u[4]; bf16x8 v; } bb;
            bb.u[0] = hs ? rcv0 : own0;
            bb.u[1] = hs ? rcv1 : own1;
            bb.u[2] = hs ? own0 : rcv0;
            bb.u[3] = hs ? own1 : rcv1;
            pf[seg] = bb.v;
        }

        // ---- O += V P'   (A = V[c][j] from LDS, B = P')
        #pragma unroll
        for (int ct = 0; ct < 8; ++ct) {
            const int c = ct * 32 + li;
            const int xc = c & 7;
            #pragma unroll
            for (int seg = 0; seg < 4; ++seg) {
                const int chs = (seg * 2 + hs) ^ xc;
                const bf16x8 vf = *(const bf16x8*)(vb + c * 64 + chs * 8);
                oacc[ct] = __builtin_amdgcn_mfma_f32_32x32x16_bf16(vf, pf[seg], oacc[ct], 0, 0, 0);
            }
        }
        __syncthreads();
    }

    // ---- finalize softmax denominators (other half only)
    ssl += __shfl_xor(ssl, 32, 64);
    const float inv = 1.f / ssl;

    // ---- epilogue: C-layout rows are channels; columns are queries
    #pragma unroll
    for (int ct = 0; ct < 8; ++ct) {
        #pragma unroll
        for (int r = 0; r < 16; ++r) {
            const int c = ct * 32 + (r & 3) + 8 * (r >> 2) + 4 * hs;
            const size_t gi = ((size_t)(b * C + c)) * NPIX + iw;
            const float o = oacc[ct][r] * inv;
            const float mv = motion[gi];
            outp[gi] = o;
            fuse_out[gi] = o * mv;
        }
    }
}

extern "C" void kernel_launch(void* const* d_in, const int* in_sizes, int n_in,
                              void* d_out, int out_size, void* d_ws, size_t ws_size,
                              hipStream_t stream) {
    const float* a1     = (const float*)d_in[0];  // appearance_1 -> k
    const float* a2     = (const float*)d_in[1];  // appearance_2 -> q
    const float* motion = (const float*)d_in[2];  // -> v, and fuse multiplier
    const float* Wq = (const float*)d_in[3];
    const float* bq = (const float*)d_in[4];
    const float* Wk = (const float*)d_in[5];
    const float* bk = (const float*)d_in[6];
    const float* Wv = (const float*)d_in[7];
    const float* bv = (const float*)d_in[8];

    float* outp = (float*)d_out;  // [fuse_out | out]

    // workspace: QT (8MB, [b][n][c]) | KT (8MB, [b][n][c]) | V (16MB, [b][c][n])
    u16* qws = (u16*)d_ws;
    u16* kws = qws + (size_t)BS * C2 * NPIX;
    u16* vws = kws + (size_t)BS * C2 * NPIX;

    const dim3 blk(256);
    proj_t<<<dim3(NPIX / 64, 2, BS), blk, 0, stream>>>(Wq, bq, a2, qws);
    proj_t<<<dim3(NPIX / 64, 2, BS), blk, 0, stream>>>(Wk, bk, a1, kws);
    proj_nat<C, C><<<dim3(NPIX / 64, C / 64, BS), blk, 0, stream>>>(Wv, bv, motion, vws);

    attn_mfma2<<<dim3(BS * (NPIX / 128)), blk, 0, stream>>>(
        qws, kws, vws, motion, outp, outp + (size_t)BS * C * NPIX);
}

// Round 4
// 386.942 us; speedup vs baseline: 7.3015x; 1.5586x over previous
//
#include <hip/hip_runtime.h>
#include <cstdint>
#include <cstddef>

#define BS   8
#define C    256
#define C2   128
#define NPIX 4096

typedef unsigned short u16;
typedef unsigned int   u32;
typedef __bf16 bf16_t;
typedef bf16_t bf16x8 __attribute__((ext_vector_type(8)));
typedef float  f32x16 __attribute__((ext_vector_type(16)));

__device__ __forceinline__ u16 f2bf(float f) {
    union { float ff; u32 i; } x; x.ff = f;
    u32 r = x.i + 0x7fffu + ((x.i >> 16) & 1u);  // RNE
    return (u16)(r >> 16);
}

// ---------------- projection, natural output [b][o][n] (used for V) --------
template <int O, int CIN>
__global__ __launch_bounds__(256)
void proj_nat(const float* __restrict__ W, const float* __restrict__ bias,
              const float* __restrict__ x, u16* __restrict__ out) {
    __shared__ float Ws[16][65];
    __shared__ float Xs[16][64];
    const int t  = threadIdx.x;
    const int tx = t & 15, ty = t >> 4;
    const int n0 = blockIdx.x * 64;
    const int o0 = blockIdx.y * 64;
    const int b  = blockIdx.z;
    float acc[4][4] = {{0.f,0.f,0.f,0.f}};
    for (int kc = 0; kc < CIN; kc += 16) {
        #pragma unroll
        for (int idx0 = 0; idx0 < 1024; idx0 += 256) {
            const int idx = idx0 + t;
            const int oo = idx >> 4, kk = idx & 15;
            Ws[kk][oo] = W[(size_t)(o0 + oo) * CIN + (kc + kk)];
        }
        #pragma unroll
        for (int idx0 = 0; idx0 < 1024; idx0 += 256) {
            const int idx = idx0 + t;
            const int kk = idx >> 6, nn = idx & 63;
            Xs[kk][nn] = x[((size_t)b * CIN + (kc + kk)) * NPIX + (n0 + nn)];
        }
        __syncthreads();
        #pragma unroll
        for (int kk = 0; kk < 16; ++kk) {
            const float a0 = Ws[kk][ty * 4 + 0];
            const float a1 = Ws[kk][ty * 4 + 1];
            const float a2 = Ws[kk][ty * 4 + 2];
            const float a3 = Ws[kk][ty * 4 + 3];
            const float4 bv = *(const float4*)&Xs[kk][tx * 4];
            acc[0][0] = fmaf(a0, bv.x, acc[0][0]); acc[0][1] = fmaf(a0, bv.y, acc[0][1]);
            acc[0][2] = fmaf(a0, bv.z, acc[0][2]); acc[0][3] = fmaf(a0, bv.w, acc[0][3]);
            acc[1][0] = fmaf(a1, bv.x, acc[1][0]); acc[1][1] = fmaf(a1, bv.y, acc[1][1]);
            acc[1][2] = fmaf(a1, bv.z, acc[1][2]); acc[1][3] = fmaf(a1, bv.w, acc[1][3]);
            acc[2][0] = fmaf(a2, bv.x, acc[2][0]); acc[2][1] = fmaf(a2, bv.y, acc[2][1]);
            acc[2][2] = fmaf(a2, bv.z, acc[2][2]); acc[2][3] = fmaf(a2, bv.w, acc[2][3]);
            acc[3][0] = fmaf(a3, bv.x, acc[3][0]); acc[3][1] = fmaf(a3, bv.y, acc[3][1]);
            acc[3][2] = fmaf(a3, bv.z, acc[3][2]); acc[3][3] = fmaf(a3, bv.w, acc[3][3]);
        }
        __syncthreads();
    }
    #pragma unroll
    for (int ii = 0; ii < 4; ++ii) {
        const float bb = bias[o0 + ty * 4 + ii];
        const size_t base = ((size_t)b * O + (o0 + ty * 4 + ii)) * NPIX + n0 + tx * 4;
        u16 tmp[4];
        #pragma unroll
        for (int jj = 0; jj < 4; ++jj) tmp[jj] = f2bf(acc[ii][jj] + bb);
        *(uint2*)&out[base] = make_uint2((u32)tmp[0] | ((u32)tmp[1] << 16),
                                         (u32)tmp[2] | ((u32)tmp[3] << 16));
    }
}

// ------------- projection, transposed output [b][n][o]  (used for Q, K) ----
__global__ __launch_bounds__(256)
void proj_t(const float* __restrict__ W, const float* __restrict__ bias,
            const float* __restrict__ x, u16* __restrict__ out) {
    __shared__ float Ws[16][65];
    __shared__ float Xs[16][64];
    __shared__ float T[64][66];
    const int t  = threadIdx.x;
    const int tx = t & 15, ty = t >> 4;
    const int n0 = blockIdx.x * 64;
    const int o0 = blockIdx.y * 64;
    const int b  = blockIdx.z;
    float acc[4][4] = {{0.f,0.f,0.f,0.f}};
    for (int kc = 0; kc < 128; kc += 16) {
        #pragma unroll
        for (int idx0 = 0; idx0 < 1024; idx0 += 256) {
            const int idx = idx0 + t;
            const int oo = idx >> 4, kk = idx & 15;
            Ws[kk][oo] = W[(size_t)(o0 + oo) * 128 + (kc + kk)];
        }
        #pragma unroll
        for (int idx0 = 0; idx0 < 1024; idx0 += 256) {
            const int idx = idx0 + t;
            const int kk = idx >> 6, nn = idx & 63;
            Xs[kk][nn] = x[((size_t)b * 128 + (kc + kk)) * NPIX + (n0 + nn)];
        }
        __syncthreads();
        #pragma unroll
        for (int kk = 0; kk < 16; ++kk) {
            const float a0 = Ws[kk][ty * 4 + 0];
            const float a1 = Ws[kk][ty * 4 + 1];
            const float a2 = Ws[kk][ty * 4 + 2];
            const float a3 = Ws[kk][ty * 4 + 3];
            const float4 bv = *(const float4*)&Xs[kk][tx * 4];
            acc[0][0] = fmaf(a0, bv.x, acc[0][0]); acc[0][1] = fmaf(a0, bv.y, acc[0][1]);
            acc[0][2] = fmaf(a0, bv.z, acc[0][2]); acc[0][3] = fmaf(a0, bv.w, acc[0][3]);
            acc[1][0] = fmaf(a1, bv.x, acc[1][0]); acc[1][1] = fmaf(a1, bv.y, acc[1][1]);
            acc[1][2] = fmaf(a1, bv.z, acc[1][2]); acc[1][3] = fmaf(a1, bv.w, acc[1][3]);
            acc[2][0] = fmaf(a2, bv.x, acc[2][0]); acc[2][1] = fmaf(a2, bv.y, acc[2][1]);
            acc[2][2] = fmaf(a2, bv.z, acc[2][2]); acc[2][3] = fmaf(a2, bv.w, acc[2][3]);
            acc[3][0] = fmaf(a3, bv.x, acc[3][0]); acc[3][1] = fmaf(a3, bv.y, acc[3][1]);
            acc[3][2] = fmaf(a3, bv.z, acc[3][2]); acc[3][3] = fmaf(a3, bv.w, acc[3][3]);
        }
        __syncthreads();
    }
    #pragma unroll
    for (int ii = 0; ii < 4; ++ii) {
        const float bb = bias[o0 + ty * 4 + ii];
        #pragma unroll
        for (int jj = 0; jj < 4; ++jj)
            T[tx * 4 + jj][ty * 4 + ii] = acc[ii][jj] + bb;
    }
    __syncthreads();
    const int n = t >> 2, oq = t & 3;
    u16 tmp[16];
    #pragma unroll
    for (int e = 0; e < 16; ++e) tmp[e] = f2bf(T[n][oq * 16 + e]);
    u16* op = out + ((size_t)b * NPIX + n0 + n) * 128 + o0 + oq * 16;
    uint4 w0, w1;
    w0.x = (u32)tmp[0]  | ((u32)tmp[1]  << 16); w0.y = (u32)tmp[2]  | ((u32)tmp[3]  << 16);
    w0.z = (u32)tmp[4]  | ((u32)tmp[5]  << 16); w0.w = (u32)tmp[6]  | ((u32)tmp[7]  << 16);
    w1.x = (u32)tmp[8]  | ((u32)tmp[9]  << 16); w1.y = (u32)tmp[10] | ((u32)tmp[11] << 16);
    w1.z = (u32)tmp[12] | ((u32)tmp[13] << 16); w1.w = (u32)tmp[14] | ((u32)tmp[15] << 16);
    *(uint4*)op = w0;
    *(uint4*)(op + 8) = w1;
}

// ----------------------------- MFMA attention v3 ---------------------------
// j-split x2 across blocks (unnormalized partials; merge kernel combines).
// Grid 512 -> 2 blocks/CU -> 2 waves/SIMD. TJ=32, K+V dbuf = 48 KB LDS.
// K LDS: [j][c] rows 256B, 16B chunks xor (j&15)        -> 2-way reads (free)
// V LDS: [c>>1][(c&1)*32+j] rows 128B, 8B chunks xor rc -> 2-way reads (free)
struct SR { uint4 k[2]; uint4 v[4]; };

__device__ __forceinline__ void stg_load(const u16* __restrict__ kg,
                                         const u16* __restrict__ vg,
                                         int jt, int t, SR& R) {
    const u16* kp = kg + (size_t)jt * 32 * 128;
    #pragma unroll
    for (int q = 0; q < 2; ++q)
        R.k[q] = *(const uint4*)(kp + (size_t)(t + 256 * q) * 8);
    const u16* vp = vg + jt * 32 + (t & 3) * 8;
    #pragma unroll
    for (int q = 0; q < 4; ++q)
        R.v[q] = *(const uint4*)(vp + (size_t)((t >> 2) + 64 * q) * NPIX);
}

__device__ __forceinline__ void stg_write(u16* __restrict__ kb, u16* __restrict__ vb,
                                          int t, const SR& R) {
    #pragma unroll
    for (int q = 0; q < 2; ++q) {
        const int idx = t + 256 * q;
        const int row = idx >> 4;
        const int ch  = (idx & 15) ^ (row & 15);
        *(uint4*)(kb + row * 128 + ch * 8) = R.k[q];
    }
    #pragma unroll
    for (int q = 0; q < 4; ++q) {
        const int c   = (t >> 2) + 64 * q;
        const int rc  = c >> 1;
        const int q8  = (c & 1) * 8 + (t & 3) * 2;
        const int x   = rc & 15;
        const int ch0 = q8 ^ x;
        const int ch1 = (q8 + 1) ^ x;
        *(uint2*)(vb + rc * 64 + ch0 * 4) = make_uint2(R.v[q].x, R.v[q].y);
        *(uint2*)(vb + rc * 64 + ch1 * 4) = make_uint2(R.v[q].z, R.v[q].w);
    }
}

__global__ __launch_bounds__(256, 2)
void attn_mfma3(const u16* __restrict__ qt,   // [BS][NPIX][C2]
                const u16* __restrict__ kt,   // [BS][NPIX][C2]
                const u16* __restrict__ vn,   // [BS][C][NPIX]
                float* __restrict__ opart0,   // partial O, j-half 0 (fuse slot)
                float* __restrict__ opart1,   // partial O, j-half 1 (out slot)
                float* __restrict__ sbuf) {   // [2][BS][NPIX] partial sums
    __shared__ u16 Kb[2][32 * 128];
    __shared__ u16 Vb[2][128 * 64];

    const int t  = threadIdx.x;
    const int w  = t >> 6;
    const int li = t & 31;
    const int hs = (t >> 5) & 1;

    const int b  = blockIdx.x & 7;                 // batch <-> XCD affinity
    const int it = (blockIdx.x >> 3) & 31;
    const int h  = blockIdx.x >> 8;                // j-half
    const int i0 = it * 128;
    const int iw = i0 + w * 32 + li;
    const int j0 = h * 2048;

    // Q fragments (persistent): B[k=c][n=i], slot (hs,e) -> c = ct*16 + hs*8 + e
    bf16x8 qf[8];
    {
        const u16* qp = qt + ((size_t)b * NPIX + iw) * C2 + hs * 8;
        #pragma unroll
        for (int ct = 0; ct < 8; ++ct) qf[ct] = *(const bf16x8*)(qp + ct * 16);
    }

    f32x16 oacc[8];
    #pragma unroll
    for (int ct = 0; ct < 8; ++ct)
        #pragma unroll
        for (int e = 0; e < 16; ++e) oacc[ct][e] = 0.f;

    const u16* ktb = kt + ((size_t)b * NPIX + j0) * C2;
    const u16* vnb = vn + (size_t)b * C * NPIX + j0;

    SR R;
    stg_load(ktb, vnb, 0, t, R);
    stg_write(&Kb[0][0], &Vb[0][0], t, R);
    stg_load(ktb, vnb, 1, t, R);
    __syncthreads();

    float ssl = 0.f;
    for (int itr = 0; itr < 64; ++itr) {
        const int cur = itr & 1;
        if (itr < 63) {
            stg_write(&Kb[cur ^ 1][0], &Vb[cur ^ 1][0], t, R);
            if (itr < 62) stg_load(ktb, vnb, itr + 2, t, R);
        }
        const u16* kb = &Kb[cur][0];
        const u16* vb = &Vb[cur][0];

        // ---- S' = K Q^T  [32j x 32i]
        f32x16 s;
        #pragma unroll
        for (int e = 0; e < 16; ++e) s[e] = 0.f;
        {
            const int xr = li & 15;
            #pragma unroll
            for (int ct = 0; ct < 8; ++ct) {
                const int ch = (ct * 2 + hs) ^ xr;
                const bf16x8 kf = *(const bf16x8*)(kb + li * 128 + ch * 8);
                s = __builtin_amdgcn_mfma_f32_32x32x16_bf16(kf, qf[ct], s, 0, 0, 0);
            }
        }

        // ---- P = exp(S'), in-lane partial sums, pack bf16 pairs
        u32 pk[8];
        #pragma unroll
        for (int n = 0; n < 8; ++n) {
            const float p0 = __expf(s[2 * n]);
            const float p1 = __expf(s[2 * n + 1]);
            ssl += p0 + p1;
            pk[n] = (u32)f2bf(p0) | ((u32)f2bf(p1) << 16);
        }

        // ---- P' -> PV B-fragments via half-swap shuffle
        bf16x8 pf[2];
        #pragma unroll
        for (int seg = 0; seg < 2; ++seg) {
            const u32 A0 = pk[4 * seg + 0], A1 = pk[4 * seg + 1];
            const u32 A2 = pk[4 * seg + 2], A3 = pk[4 * seg + 3];
            const u32 own0 = hs ? A2 : A0, own1 = hs ? A3 : A1;
            const u32 snd0 = hs ? A0 : A2, snd1 = hs ? A1 : A3;
            const u32 rcv0 = (u32)__shfl_xor((int)snd0, 32, 64);
            const u32 rcv1 = (u32)__shfl_xor((int)snd1, 32, 64);
            union { u32 u[4]; bf16x8 v; } bb;
            bb.u[0] = hs ? rcv0 : own0;
            bb.u[1] = hs ? rcv1 : own1;
            bb.u[2] = hs ? own0 : rcv0;
            bb.u[3] = hs ? own1 : rcv1;
            pf[seg] = bb.v;
        }

        // ---- O += V P'  (A = V from LDS as 2x b64, 2-way conflict-free)
        #pragma unroll
        for (int ct = 0; ct < 8; ++ct) {
            const int c  = ct * 32 + li;
            const int rc = c >> 1;
            const int x  = rc & 15;
            const u16* vr = vb + rc * 64;
            const int cb = (c & 1) * 8 + hs * 2;
            #pragma unroll
            for (int seg = 0; seg < 2; ++seg) {
                const int q8  = cb + seg * 4;
                const int ch0 = q8 ^ x;
                const int ch1 = (q8 + 1) ^ x;
                union { uint2 g[2]; bf16x8 v8; } u;
                u.g[0] = *(const uint2*)(vr + ch0 * 4);
                u.g[1] = *(const uint2*)(vr + ch1 * 4);
                oacc[ct] = __builtin_amdgcn_mfma_f32_32x32x16_bf16(u.v8, pf[seg], oacc[ct], 0, 0, 0);
            }
        }
        __syncthreads();
    }

    // ---- partial denominators: combine the two hs halves, store (hs=0 lanes)
    ssl += __shfl_xor(ssl, 32, 64);
    if (hs == 0) sbuf[((size_t)h * BS + b) * NPIX + iw] = ssl;

    // ---- store unnormalized partial O (merge kernel normalizes + fuses)
    float* op = h ? opart1 : opart0;
    #pragma unroll
    for (int ct = 0; ct < 8; ++ct) {
        #pragma unroll
        for (int r = 0; r < 16; ++r) {
            const int c = ct * 32 + (r & 3) + 8 * (r >> 2) + 4 * hs;
            op[((size_t)b * C + c) * NPIX + iw] = oacc[ct][r];
        }
    }
}

// ---- merge: out = (O1+O2)/(s1+s2); fuse = out*motion -----------------------
__global__ __launch_bounds__(256)
void attn_merge(float* __restrict__ fuse,    // in: O1 partial, out: fuse_out
                float* __restrict__ outp,    // in: O2 partial, out: out
                const float* __restrict__ motion,
                const float* __restrict__ sbuf) {
    const size_t idx = ((size_t)blockIdx.x * 256 + threadIdx.x) * 4;
    const int n = (int)(idx & (NPIX - 1));
    const int b = (int)(idx >> 20);
    const float4 o1 = *(const float4*)(fuse + idx);
    const float4 o2 = *(const float4*)(outp + idx);
    const float4 sa = *(const float4*)(sbuf + (size_t)b * NPIX + n);
    const float4 sb = *(const float4*)(sbuf + (size_t)(BS + b) * NPIX + n);
    float4 o;
    o.x = (o1.x + o2.x) / (sa.x + sb.x);
    o.y = (o1.y + o2.y) / (sa.y + sb.y);
    o.z = (o1.z + o2.z) / (sa.z + sb.z);
    o.w = (o1.w + o2.w) / (sa.w + sb.w);
    const float4 mv = *(const float4*)(motion + idx);
    *(float4*)(outp + idx) = o;
    *(float4*)(fuse + idx) = make_float4(o.x * mv.x, o.y * mv.y, o.z * mv.z, o.w * mv.w);
}

extern "C" void kernel_launch(void* const* d_in, const int* in_sizes, int n_in,
                              void* d_out, int out_size, void* d_ws, size_t ws_size,
                              hipStream_t stream) {
    const float* a1     = (const float*)d_in[0];  // appearance_1 -> k
    const float* a2     = (const float*)d_in[1];  // appearance_2 -> q
    const float* motion = (const float*)d_in[2];  // -> v, and fuse multiplier
    const float* Wq = (const float*)d_in[3];
    const float* bq = (const float*)d_in[4];
    const float* Wk = (const float*)d_in[5];
    const float* bk = (const float*)d_in[6];
    const float* Wv = (const float*)d_in[7];
    const float* bv = (const float*)d_in[8];

    float* outp = (float*)d_out;  // [fuse_out | out]
    float* slot0 = outp;                              // fuse slot / O1 partial
    float* slot1 = outp + (size_t)BS * C * NPIX;      // out slot  / O2 partial

    // workspace: QT (8MB) | KT (8MB) | V (16MB) | sbuf (256KB)
    u16* qws = (u16*)d_ws;
    u16* kws = qws + (size_t)BS * C2 * NPIX;
    u16* vws = kws + (size_t)BS * C2 * NPIX;
    float* sbuf = (float*)(vws + (size_t)BS * C * NPIX);

    const dim3 blk(256);
    proj_t<<<dim3(NPIX / 64, 2, BS), blk, 0, stream>>>(Wq, bq, a2, qws);
    proj_t<<<dim3(NPIX / 64, 2, BS), blk, 0, stream>>>(Wk, bk, a1, kws);
    proj_nat<C, C><<<dim3(NPIX / 64, C / 64, BS), blk, 0, stream>>>(Wv, bv, motion, vws);

    attn_mfma3<<<dim3(512), blk, 0, stream>>>(qws, kws, vws, slot0, slot1, sbuf);

    attn_merge<<<dim3((BS * C * NPIX) / 1024), blk, 0, stream>>>(
        slot0, slot1, motion, sbuf);
}